// Round 17
// baseline (182.225 us; speedup 1.0000x reference)
//
#include <hip/hip_runtime.h>
#include <hip/hip_bf16.h>

#define HB 16
#define DH 64
#define SQ 2048
#define BB 2

using f32x4 = __attribute__((ext_vector_type(4))) float;
using f32x16 = __attribute__((ext_vector_type(16))) float;
using s16x8 = __attribute__((ext_vector_type(8))) short;

__device__ __forceinline__ unsigned bfr(float f) {
    union { float f; unsigned u; } v; v.f = f;
    return (v.u + 0x7fffu + ((v.u >> 16) & 1u)) >> 16;
}
__device__ __forceinline__ unsigned pk2(float a, float b) { return bfr(a) | (bfr(b) << 16); }
__device__ __forceinline__ short f2bf(float f) { return (short)bfr(f); }

// row-stride-64-short tiles, 16B-chunk XOR swizzle s = r&7
__device__ __forceinline__ int swz64(int r, int c) {
    return r * 64 + ((((c >> 3) ^ (r & 7)) & 7) << 3) + (c & 7);
}
// row-stride-32-short tiles: chunk ^= (r>>1)&3
__device__ __forceinline__ int swz32(int r, int c) {
    return r * 32 + ((((c >> 3) ^ ((r >> 1) & 3)) & 3) << 3) + (c & 7);
}

__device__ __forceinline__ void gll16(const short* g, short* l) {
    __builtin_amdgcn_global_load_lds(
        (const __attribute__((address_space(1))) unsigned int*)(uintptr_t)g,
        (__attribute__((address_space(3))) unsigned int*)(uintptr_t)l, 16, 0, 0);
}

// ---- combined pre-pass: X fp32->bf16 (bid<2048) | W -> WT bf16 (bid>=2048) ----
__device__ __forceinline__ int swzT(int n, int k) {
    return n * 64 + ((((k >> 3) ^ ((n >> 2) & 7)) & 7) << 3) + (k & 7);
}
__global__ __launch_bounds__(256) void cvt_all(
    const float* __restrict__ x, const float* __restrict__ w,
    short* __restrict__ xb, short* __restrict__ wt)
{
    __shared__ short T[64 * 64];
    int bid = blockIdx.x;
    int t = threadIdx.x;
    if (bid < 2048) {
        int i = (bid * 256 + t) * 8;
        float4 v0 = *(const float4*)&x[i];
        float4 v1 = *(const float4*)&x[i + 4];
        uint4 u;
        u.x = pk2(v0.x, v0.y); u.y = pk2(v0.z, v0.w);
        u.z = pk2(v1.x, v1.y); u.w = pk2(v1.z, v1.w);
        *(uint4*)&xb[i] = u;
        return;
    }
    bid -= 2048;                                // 768 = 3 * 16 * 16
    int nt = bid & 15, kt = (bid >> 4) & 15, p = bid >> 8;
    const float* wp = w + p * 1048576 + (kt * 64) * 1024 + nt * 64;
    short* wtp = wt + p * 1048576 + (nt * 64) * 1024 + kt * 64;
#pragma unroll
    for (int ps = 0; ps < 4; ps++) {
        int idx = ps * 1024 + t * 4;
        int r = idx >> 6, c = idx & 63;
        float4 v = *(const float4*)&wp[r * 1024 + c];
        T[swzT(c + 0, r)] = f2bf(v.x);
        T[swzT(c + 1, r)] = f2bf(v.y);
        T[swzT(c + 2, r)] = f2bf(v.z);
        T[swzT(c + 3, r)] = f2bf(v.w);
    }
    __syncthreads();
#pragma unroll
    for (int ps = 0; ps < 2; ps++) {
        int idx = ps * 2048 + t * 8;
        int n = idx >> 6, kc = idx & 63;
        s16x8 vv = *(const s16x8*)&T[swzT(n, kc)];
        *(s16x8*)&wtp[n * 1024 + kc] = vv;
    }
}

// ---- main GEMM: p-fused 128x384, 3-buffer distance-2, counted vmcnt ----
__global__ __launch_bounds__(512, 1) void qkv_gemm(
    const short* __restrict__ xb, const short* __restrict__ wt, short* __restrict__ ws)
{
    __shared__ short Xs[3][128 * 32];    // 24 KB
    __shared__ short Ns[3][384 * 32];    // 72 KB
    const int tid = threadIdx.x;
    const int wv = tid >> 6, ln = tid & 63;
    const int bid = blockIdx.x;
    const int swz = (bid & 7) * 32 + (bid >> 3);  // XCD = 32 m-tiles x 1 n-group
    const int m0 = (swz & 31) * 128;
    const int n0 = (swz >> 5) * 128;

    const int wm = (wv >> 2) * 64, wn = (wv & 3) * 96;
    const int lr = ln & 15, lk = (ln >> 4) * 8;
    const int srow = tid >> 2;
    const int csw = (((tid & 3) ^ ((tid >> 3) & 3)) & 3) * 8;

    f32x4 acc[4][6] = {};

#define GSTAGE(k0_, bf_) do {                                                   \
        gll16(&xb[(m0 + srow) * 1024 + (k0_) + csw], &Xs[bf_][wv * 512]);       \
        _Pragma("unroll")                                                       \
        for (int p_ = 0; p_ < 3; p_++)                                          \
            gll16(&wt[p_ * 1048576 + (n0 + srow) * 1024 + (k0_) + csw],         \
                  &Ns[bf_][p_ * 4096 + wv * 512]);                              \
    } while (0)

#define GCOMP(bf_) do {                                                         \
        s16x8 af[4], bg[6];                                                     \
        _Pragma("unroll")                                                       \
        for (int i = 0; i < 4; i++)                                             \
            af[i] = *(const s16x8*)&Xs[bf_][swz32(wm + i * 16 + lr, lk)];       \
        _Pragma("unroll")                                                       \
        for (int j = 0; j < 6; j++)                                             \
            bg[j] = *(const s16x8*)&Ns[bf_][swz32(wn + j * 16 + lr, lk)];       \
        __builtin_amdgcn_s_setprio(1);                                          \
        _Pragma("unroll")                                                       \
        for (int i = 0; i < 4; i++)                                             \
            _Pragma("unroll")                                                   \
            for (int j = 0; j < 6; j++)                                         \
                acc[i][j] = __builtin_amdgcn_mfma_f32_16x16x32_bf16(af[i], bg[j], acc[i][j], 0, 0, 0); \
        __builtin_amdgcn_s_setprio(0);                                          \
    } while (0)

    GSTAGE(0, 0);
    GSTAGE(32, 1);
    int cur = 0;
    for (int t = 0; t < 31; t++) {
        asm volatile("s_waitcnt vmcnt(4)\n\ts_barrier" ::: "memory");
        int pre = cur + 2; if (pre >= 3) pre -= 3;
        if (t < 30) GSTAGE((t + 2) * 32, pre);
        GCOMP(cur);
        cur = (cur == 2) ? 0 : cur + 1;
    }
    asm volatile("s_waitcnt vmcnt(0)\n\ts_barrier" ::: "memory");
    GCOMP(cur);    // tile 31

    short* qws = ws;
    short* kws = ws + BB * HB * SQ * DH;
    short* vtw = ws + 2 * BB * HB * SQ * DH;
#pragma unroll
    for (int i = 0; i < 4; i++) {
#pragma unroll
        for (int r = 0; r < 4; r++) {
            int row = m0 + wm + i * 16 + (ln >> 4) * 4 + r;
            int b = row >> 11, s = row & 2047;
#pragma unroll
            for (int j = 0; j < 6; j++) {
                int c = wn + j * 16 + (ln & 15);
                int p = c >> 7;
                int gcol = n0 + (c & 127);
                int h = gcol >> 6, dhi = gcol & 63;
                float v = acc[i][j][r];
                if (p == 0)      qws[((b * HB + h) * SQ + s) * DH + dhi] = f2bf(v * 0.1803368801f);
                else if (p == 1) kws[((b * HB + h) * SQ + s) * DH + dhi] = f2bf(v);
                else             vtw[((b * HB + h) * DH + dhi) * SQ + s] = f2bf(v);
            }
        }
    }
#undef GSTAGE
#undef GCOMP
}

// ---- flash attention: 16 waves = 4 q-subtiles x 4 kv-groups, KVBLK=32,
//      per-group dbuf, 32 waves/CU, additive 4-way merge ----
__global__ __launch_bounds__(1024, 8) void attn(
    const short* __restrict__ qws, const short* __restrict__ kws,
    const short* __restrict__ vtw, float* __restrict__ out)
{
    __shared__ __align__(16) short smem[32768];   // 64KB: [g 4][buf 2][K 2048 | V 2048]
    __shared__ float Lx[3][4][32];
    const int tid = threadIdx.x, wv = tid >> 6, ln = tid & 63;
    const int ws_ = wv & 3, g = wv >> 2;          // q-subtile 0..3, kv-group 0..3
    const int bid = blockIdx.x;
    const int swz = (bid & 7) * 64 + (bid >> 3);  // bijective (512%8==0)
    const int qt = swz & 15, bh = swz >> 4;
    const short* Q = qws + bh * SQ * DH;
    const short* K = kws + bh * SQ * DH;
    const short* VT = vtw + bh * DH * SQ;
    const int lq = ln & 31, lg = ln >> 5;
    const int q0w = qt * 128 + ws_ * 32;
    const int kvbase = g * 512;

    const int klo = (ws_ * 8 + (ln >> 3)) * DH + (((ln & 7) ^ ((ln >> 3) & 7)) & 7) * 8;
    const int vr = ln >> 2;
    const int vlo = (ws_ * 16 + vr) * SQ + (((ln & 3) ^ ((vr >> 1) & 3)) & 3) * 8;

    s16x8 qf[4];
#pragma unroll
    for (int ks = 0; ks < 4; ks++)
        qf[ks] = *(const s16x8*)&Q[(q0w + lq) * DH + ks * 16 + lg * 8];

    f32x16 o0 = {}, o1 = {};
    float l = 0.f;

#define STAGE(t, bf_) do {                                          \
        short* Kd = smem + g * 8192 + (bf_) * 4096;                 \
        const short* Kt = K + (kvbase + (t) * 32) * DH;             \
        const short* Vt = VT + kvbase + (t) * 32;                   \
        gll16(Kt + klo, Kd + ws_ * 512);                            \
        gll16(Vt + vlo, Kd + 2048 + ws_ * 512);                     \
    } while (0)

#define COMPUTE(bf_) do {                                                      \
        const short* Kr = smem + g * 8192 + (bf_) * 4096;                      \
        const short* Vr = Kr + 2048;                                           \
        f32x16 s = {};                                                         \
        __builtin_amdgcn_s_setprio(1);                                         \
        _Pragma("unroll")                                                      \
        for (int ks = 0; ks < 4; ks++) {                                       \
            s16x8 ka = *(const s16x8*)&Kr[swz64(lq, ks * 16 + lg * 8)];        \
            s = __builtin_amdgcn_mfma_f32_32x32x16_bf16(ka, qf[ks], s, 0, 0, 0); \
        }                                                                      \
        __builtin_amdgcn_s_setprio(0);                                         \
        float p[16];                                                           \
        _Pragma("unroll")                                                      \
        for (int i = 0; i < 16; i++) p[i] = __builtin_amdgcn_exp2f(s[i]);      \
        float a0 = 0.f, a1 = 0.f, a2 = 0.f, a3 = 0.f;                          \
        _Pragma("unroll")                                                      \
        for (int i = 0; i < 16; i += 4) {                                      \
            a0 += p[i]; a1 += p[i + 1]; a2 += p[i + 2]; a3 += p[i + 3];        \
        }                                                                      \
        l += (a0 + a1) + (a2 + a3);                                            \
        unsigned u[8];                                                         \
        _Pragma("unroll")                                                      \
        for (int qd = 0; qd < 4; qd++) {                                       \
            asm("v_cvt_pk_bf16_f32 %0, %1, %2" : "=v"(u[qd * 2]) : "v"(p[qd * 4 + 0]), "v"(p[qd * 4 + 1])); \
            asm("v_cvt_pk_bf16_f32 %0, %1, %2" : "=v"(u[qd * 2 + 1]) : "v"(p[qd * 4 + 2]), "v"(p[qd * 4 + 3])); \
        }                                                                      \
        _Pragma("unroll")                                                      \
        for (int m2 = 0; m2 < 2; m2++)                                         \
            _Pragma("unroll")                                                  \
            for (int j = 0; j < 2; j++)                                        \
                asm("v_permlane32_swap_b32 %0, %1"                             \
                    : "+v"(u[(2 * m2) * 2 + j]), "+v"(u[(2 * m2 + 1) * 2 + j])); \
        __builtin_amdgcn_s_setprio(1);                                         \
        _Pragma("unroll")                                                      \
        for (int ks = 0; ks < 2; ks++) {                                       \
            union { unsigned w[4]; s16x8 v; } pa;                              \
            pa.w[0] = u[4 * ks + 0];                                           \
            pa.w[1] = u[4 * ks + 1];                                           \
            pa.w[2] = u[4 * ks + 2];                                           \
            pa.w[3] = u[4 * ks + 3];                                           \
            s16x8 vb0 = *(const s16x8*)&Vr[swz32(lq, ks * 16 + lg * 8)];       \
            s16x8 vb1 = *(const s16x8*)&Vr[swz32(32 + lq, ks * 16 + lg * 8)];  \
            o0 = __builtin_amdgcn_mfma_f32_32x32x16_bf16(pa.v, vb0, o0, 0, 0, 0); \
            o1 = __builtin_amdgcn_mfma_f32_32x32x16_bf16(pa.v, vb1, o1, 0, 0, 0); \
        }                                                                      \
        __builtin_amdgcn_s_setprio(0);                                         \
    } while (0)

    STAGE(0, 0);
    __syncthreads();
    for (int t = 0; t < 16; t++) {
        int cur = t & 1;
        if (t < 15) STAGE(t + 1, cur ^ 1);
        COMPUTE(cur);
        __syncthreads();
    }

    // 4-way additive merge (no-max softmax): two LDS phases (o0, then o1)
    float lt = l + __shfl_xor(l, 32);     // valid for q-col = lq
    float* Lf = (float*)smem;             // 16384 floats available
    if (g > 0) {
        int base = ((g - 1) * 4 + ws_) * 1024;
#pragma unroll
        for (int r = 0; r < 16; r++) Lf[base + r * 64 + ln] = o0[r];
        if (lg == 0) Lx[g - 1][ws_][lq] = lt;
    }
    __syncthreads();
    float inv = 0.f;
    if (g == 0) {
        inv = 1.0f / (lt + Lx[0][ws_][lq] + Lx[1][ws_][lq] + Lx[2][ws_][lq]);
#pragma unroll
        for (int r = 0; r < 16; r++)
            o0[r] += Lf[ws_ * 1024 + r * 64 + ln]
                   + Lf[(4 + ws_) * 1024 + r * 64 + ln]
                   + Lf[(8 + ws_) * 1024 + r * 64 + ln];
    }
    __syncthreads();
    if (g > 0) {
        int base = ((g - 1) * 4 + ws_) * 1024;
#pragma unroll
        for (int r = 0; r < 16; r++) Lf[base + r * 64 + ln] = o1[r];
    }
    __syncthreads();
    if (g == 0) {
        const int b = bh >> 4, h = bh & 15;
#pragma unroll
        for (int r = 0; r < 16; r++) {
            float v1 = o1[r] + Lf[ws_ * 1024 + r * 64 + ln]
                             + Lf[(4 + ws_) * 1024 + r * 64 + ln]
                             + Lf[(8 + ws_) * 1024 + r * 64 + ln];
            int qrow = (r & 3) + 8 * (r >> 2) + 4 * lg;
            float iv = __shfl(inv, qrow);
            float* op = out + ((long)(b * SQ + q0w + qrow)) * 1024 + h * 64 + lq;
            op[0]  = o0[r] * iv;
            op[32] = v1 * iv;
        }
    }
#undef STAGE
#undef COMPUTE
}

extern "C" void kernel_launch(void* const* d_in, const int* in_sizes, int n_in,
                              void* d_out, int out_size, void* d_ws, size_t ws_size,
                              hipStream_t stream) {
    const float* x = (const float*)d_in[0];
    const float* w = (const float*)d_in[1];
    short* ws = (short*)d_ws;
    short* xbf = (short*)d_out;                  // d_out as scratch; attn overwrites last
    short* wtb = (short*)d_out + 4194304;
    cvt_all<<<2816, 256, 0, stream>>>(x, w, xbf, wtb);
    qkv_gemm<<<256, 512, 0, stream>>>(xbf, wtb, ws);
    attn<<<512, 1024, 0, stream>>>(ws, ws + BB * HB * SQ * DH,
                                   ws + 2 * BB * HB * SQ * DH, (float*)d_out);
}

// Round 18
// 89.988 us; speedup vs baseline: 2.0250x; 2.0250x over previous
//
#include <hip/hip_runtime.h>
#include <hip/hip_bf16.h>

#define HB 16
#define DH 64
#define SQ 2048
#define BB 2

using f32x4 = __attribute__((ext_vector_type(4))) float;
using f32x16 = __attribute__((ext_vector_type(16))) float;
using s16x8 = __attribute__((ext_vector_type(8))) short;

__device__ __forceinline__ unsigned bfr(float f) {
    union { float f; unsigned u; } v; v.f = f;
    return (v.u + 0x7fffu + ((v.u >> 16) & 1u)) >> 16;
}
__device__ __forceinline__ unsigned pk2(float a, float b) { return bfr(a) | (bfr(b) << 16); }
__device__ __forceinline__ short f2bf(float f) { return (short)bfr(f); }

// row-stride-64-short tiles, 16B-chunk XOR swizzle s = r&7
__device__ __forceinline__ int swz64(int r, int c) {
    return r * 64 + ((((c >> 3) ^ (r & 7)) & 7) << 3) + (c & 7);
}
// row-stride-32-short tiles: chunk ^= (r>>1)&3
__device__ __forceinline__ int swz32(int r, int c) {
    return r * 32 + ((((c >> 3) ^ ((r >> 1) & 3)) & 3) << 3) + (c & 7);
}

__device__ __forceinline__ void gll16(const short* g, short* l) {
    __builtin_amdgcn_global_load_lds(
        (const __attribute__((address_space(1))) unsigned int*)(uintptr_t)g,
        (__attribute__((address_space(3))) unsigned int*)(uintptr_t)l, 16, 0, 0);
}

// ---- combined pre-pass: X fp32->bf16 (bid<2048) | W -> WT bf16 (bid>=2048) ----
__device__ __forceinline__ int swzT(int n, int k) {
    return n * 64 + ((((k >> 3) ^ ((n >> 2) & 7)) & 7) << 3) + (k & 7);
}
__global__ __launch_bounds__(256) void cvt_all(
    const float* __restrict__ x, const float* __restrict__ w,
    short* __restrict__ xb, short* __restrict__ wt)
{
    __shared__ short T[64 * 64];
    int bid = blockIdx.x;
    int t = threadIdx.x;
    if (bid < 2048) {
        int i = (bid * 256 + t) * 8;
        float4 v0 = *(const float4*)&x[i];
        float4 v1 = *(const float4*)&x[i + 4];
        uint4 u;
        u.x = pk2(v0.x, v0.y); u.y = pk2(v0.z, v0.w);
        u.z = pk2(v1.x, v1.y); u.w = pk2(v1.z, v1.w);
        *(uint4*)&xb[i] = u;
        return;
    }
    bid -= 2048;                                // 768 = 3 * 16 * 16
    int nt = bid & 15, kt = (bid >> 4) & 15, p = bid >> 8;
    const float* wp = w + p * 1048576 + (kt * 64) * 1024 + nt * 64;
    short* wtp = wt + p * 1048576 + (nt * 64) * 1024 + kt * 64;
#pragma unroll
    for (int ps = 0; ps < 4; ps++) {
        int idx = ps * 1024 + t * 4;
        int r = idx >> 6, c = idx & 63;
        float4 v = *(const float4*)&wp[r * 1024 + c];
        T[swzT(c + 0, r)] = f2bf(v.x);
        T[swzT(c + 1, r)] = f2bf(v.y);
        T[swzT(c + 2, r)] = f2bf(v.z);
        T[swzT(c + 3, r)] = f2bf(v.w);
    }
    __syncthreads();
#pragma unroll
    for (int ps = 0; ps < 2; ps++) {
        int idx = ps * 2048 + t * 8;
        int n = idx >> 6, kc = idx & 63;
        s16x8 vv = *(const s16x8*)&T[swzT(n, kc)];
        *(s16x8*)&wtp[n * 1024 + kc] = vv;
    }
}

// ---- main GEMM: p-fused 128x384, 3-buffer distance-2, counted vmcnt ----
__global__ __launch_bounds__(512, 1) void qkv_gemm(
    const short* __restrict__ xb, const short* __restrict__ wt, short* __restrict__ ws)
{
    __shared__ short Xs[3][128 * 32];    // 24 KB
    __shared__ short Ns[3][384 * 32];    // 72 KB
    const int tid = threadIdx.x;
    const int wv = tid >> 6, ln = tid & 63;
    const int bid = blockIdx.x;
    const int swz = (bid & 7) * 32 + (bid >> 3);  // XCD = 32 m-tiles x 1 n-group
    const int m0 = (swz & 31) * 128;
    const int n0 = (swz >> 5) * 128;

    const int wm = (wv >> 2) * 64, wn = (wv & 3) * 96;
    const int lr = ln & 15, lk = (ln >> 4) * 8;
    const int srow = tid >> 2;
    const int csw = (((tid & 3) ^ ((tid >> 3) & 3)) & 3) * 8;

    f32x4 acc[4][6] = {};

#define GSTAGE(k0_, bf_) do {                                                   \
        gll16(&xb[(m0 + srow) * 1024 + (k0_) + csw], &Xs[bf_][wv * 512]);       \
        _Pragma("unroll")                                                       \
        for (int p_ = 0; p_ < 3; p_++)                                          \
            gll16(&wt[p_ * 1048576 + (n0 + srow) * 1024 + (k0_) + csw],         \
                  &Ns[bf_][p_ * 4096 + wv * 512]);                              \
    } while (0)

#define GCOMP(bf_) do {                                                         \
        s16x8 af[4], bg[6];                                                     \
        _Pragma("unroll")                                                       \
        for (int i = 0; i < 4; i++)                                             \
            af[i] = *(const s16x8*)&Xs[bf_][swz32(wm + i * 16 + lr, lk)];       \
        _Pragma("unroll")                                                       \
        for (int j = 0; j < 6; j++)                                             \
            bg[j] = *(const s16x8*)&Ns[bf_][swz32(wn + j * 16 + lr, lk)];       \
        __builtin_amdgcn_s_setprio(1);                                          \
        _Pragma("unroll")                                                       \
        for (int i = 0; i < 4; i++)                                             \
            _Pragma("unroll")                                                   \
            for (int j = 0; j < 6; j++)                                         \
                acc[i][j] = __builtin_amdgcn_mfma_f32_16x16x32_bf16(af[i], bg[j], acc[i][j], 0, 0, 0); \
        __builtin_amdgcn_s_setprio(0);                                          \
    } while (0)

    GSTAGE(0, 0);
    GSTAGE(32, 1);
    int cur = 0;
    for (int t = 0; t < 31; t++) {
        asm volatile("s_waitcnt vmcnt(4)\n\ts_barrier" ::: "memory");
        int pre = cur + 2; if (pre >= 3) pre -= 3;
        if (t < 30) GSTAGE((t + 2) * 32, pre);
        GCOMP(cur);
        cur = (cur == 2) ? 0 : cur + 1;
    }
    asm volatile("s_waitcnt vmcnt(0)\n\ts_barrier" ::: "memory");
    GCOMP(cur);    // tile 31

    short* qws = ws;
    short* kws = ws + BB * HB * SQ * DH;
    short* vtw = ws + 2 * BB * HB * SQ * DH;
#pragma unroll
    for (int i = 0; i < 4; i++) {
#pragma unroll
        for (int r = 0; r < 4; r++) {
            int row = m0 + wm + i * 16 + (ln >> 4) * 4 + r;
            int b = row >> 11, s = row & 2047;
#pragma unroll
            for (int j = 0; j < 6; j++) {
                int c = wn + j * 16 + (ln & 15);
                int p = c >> 7;
                int gcol = n0 + (c & 127);
                int h = gcol >> 6, dhi = gcol & 63;
                float v = acc[i][j][r];
                if (p == 0)      qws[((b * HB + h) * SQ + s) * DH + dhi] = f2bf(v * 0.1803368801f);
                else if (p == 1) kws[((b * HB + h) * SQ + s) * DH + dhi] = f2bf(v);
                else             vtw[((b * HB + h) * DH + dhi) * SQ + s] = f2bf(v);
            }
        }
    }
#undef GSTAGE
#undef GCOMP
}

// ---- flash attention: KVBLK=32, quad-buffered distance-3, counted vmcnt,
//      T15 pipeline; 4 q-subtiles x 2 kv-groups ----
__global__ __launch_bounds__(512) void attn(
    const short* __restrict__ qws, const short* __restrict__ kws,
    const short* __restrict__ vtw, float* __restrict__ out)
{
    __shared__ __align__(16) short smem[32768];   // 64KB: [g 2][buf 4][K 2048 | V 2048]
    __shared__ float Lx[4][32];
    const int tid = threadIdx.x, wv = tid >> 6, ln = tid & 63;
    const int ws_ = wv & 3, g = wv >> 2;
    const int bid = blockIdx.x;
    const int swz = (bid & 7) * 64 + (bid >> 3);  // bijective (512%8==0)
    const int qt = swz & 15, bh = swz >> 4;
    const short* Q = qws + bh * SQ * DH;
    const short* K = kws + bh * SQ * DH;
    const short* VT = vtw + bh * DH * SQ;
    const int lq = ln & 31, lg = ln >> 5;
    const int q0w = qt * 128 + ws_ * 32;
    const int kvbase = g * 1024;

    const int klo = (ws_ * 8 + (ln >> 3)) * DH + (((ln & 7) ^ ((ln >> 3) & 7)) & 7) * 8;
    const int vr = ln >> 2;
    const int vlo = (ws_ * 16 + vr) * SQ + (((ln & 3) ^ ((vr >> 1) & 3)) & 3) * 8;

    s16x8 qf[4];
#pragma unroll
    for (int ks = 0; ks < 4; ks++)
        qf[ks] = *(const s16x8*)&Q[(q0w + lq) * DH + ks * 16 + lg * 8];

    f32x16 o0 = {}, o1 = {};
    float l = 0.f;

#define STAGE(t, bf_) do {                                          \
        short* Kd = smem + g * 16384 + (bf_) * 4096;                \
        const short* Kt = K + (kvbase + (t) * 32) * DH;             \
        const short* Vt = VT + kvbase + (t) * 32;                   \
        gll16(Kt + klo, Kd + ws_ * 512);                            \
        gll16(Vt + vlo, Kd + 2048 + ws_ * 512);                     \
    } while (0)

#define QKT(bf_, S_) do {                                                      \
        const short* Kr = smem + g * 16384 + (bf_) * 4096;                     \
        __builtin_amdgcn_s_setprio(1);                                         \
        _Pragma("unroll")                                                      \
        for (int ks = 0; ks < 4; ks++) {                                       \
            s16x8 ka = *(const s16x8*)&Kr[swz64(lq, ks * 16 + lg * 8)];        \
            S_ = __builtin_amdgcn_mfma_f32_32x32x16_bf16(ka, qf[ks], S_, 0, 0, 0); \
        }                                                                      \
        __builtin_amdgcn_s_setprio(0);                                         \
    } while (0)

#define SMPV(bf_, S_) do {                                                     \
        const short* Vr = smem + g * 16384 + (bf_) * 4096 + 2048;              \
        float p[16];                                                           \
        _Pragma("unroll")                                                      \
        for (int i = 0; i < 16; i++) p[i] = __builtin_amdgcn_exp2f(S_[i]);     \
        float a0 = 0.f, a1 = 0.f, a2 = 0.f, a3 = 0.f;                          \
        _Pragma("unroll")                                                      \
        for (int i = 0; i < 16; i += 4) {                                      \
            a0 += p[i]; a1 += p[i + 1]; a2 += p[i + 2]; a3 += p[i + 3];        \
        }                                                                      \
        l += (a0 + a1) + (a2 + a3);                                            \
        unsigned u[8];                                                         \
        _Pragma("unroll")                                                      \
        for (int qd = 0; qd < 4; qd++) {                                       \
            asm("v_cvt_pk_bf16_f32 %0, %1, %2" : "=v"(u[qd * 2]) : "v"(p[qd * 4 + 0]), "v"(p[qd * 4 + 1])); \
            asm("v_cvt_pk_bf16_f32 %0, %1, %2" : "=v"(u[qd * 2 + 1]) : "v"(p[qd * 4 + 2]), "v"(p[qd * 4 + 3])); \
        }                                                                      \
        _Pragma("unroll")                                                      \
        for (int m2 = 0; m2 < 2; m2++)                                         \
            _Pragma("unroll")                                                  \
            for (int j = 0; j < 2; j++)                                        \
                asm("v_permlane32_swap_b32 %0, %1"                             \
                    : "+v"(u[(2 * m2) * 2 + j]), "+v"(u[(2 * m2 + 1) * 2 + j])); \
        __builtin_amdgcn_s_setprio(1);                                         \
        _Pragma("unroll")                                                      \
        for (int ks = 0; ks < 2; ks++) {                                       \
            union { unsigned w[4]; s16x8 v; } pa;                              \
            pa.w[0] = u[4 * ks + 0];                                           \
            pa.w[1] = u[4 * ks + 1];                                           \
            pa.w[2] = u[4 * ks + 2];                                           \
            pa.w[3] = u[4 * ks + 3];                                           \
            s16x8 vb0 = *(const s16x8*)&Vr[swz32(lq, ks * 16 + lg * 8)];       \
            s16x8 vb1 = *(const s16x8*)&Vr[swz32(32 + lq, ks * 16 + lg * 8)];  \
            o0 = __builtin_amdgcn_mfma_f32_32x32x16_bf16(pa.v, vb0, o0, 0, 0, 0); \
            o1 = __builtin_amdgcn_mfma_f32_32x32x16_bf16(pa.v, vb1, o1, 0, 0, 0); \
        }                                                                      \
        __builtin_amdgcn_s_setprio(0);                                         \
    } while (0)

    STAGE(0, 0);
    STAGE(1, 1);
    STAGE(2, 2);
    // bufs 0,1 complete; buf 2 in flight
    asm volatile("s_waitcnt vmcnt(2)\n\ts_barrier" ::: "memory");
    f32x16 sA = {}, sB = {};
    QKT(0, sA);
#pragma unroll
    for (int t = 0; t < 32; t++) {
        if (t < 29) STAGE(t + 3, (t + 3) & 3);       // distance-3 prefetch
        if (t < 31) {
            if (t & 1) QKT((t + 1) & 3, sA);          // buf t+1 guaranteed done
            else       QKT((t + 1) & 3, sB);
        }
        if (t & 1) SMPV(t & 3, sB);
        else       SMPV(t & 3, sA);
        if (t & 1) sB = (f32x16){};
        else       sA = (f32x16){};
        // counted wait: buf t+2 completes, buf t+3 stays in flight
        if (t < 29) asm volatile("s_waitcnt vmcnt(2)\n\ts_barrier" ::: "memory");
        else        asm volatile("s_waitcnt vmcnt(0)\n\ts_barrier" ::: "memory");
    }

    float lt = l + __shfl_xor(l, 32);
    float* Lf = (float*)smem;
    if (g == 1) {
#pragma unroll
        for (int r = 0; r < 16; r++) {
            Lf[ws_ * 1024 + r * 64 + ln] = o0[r];
            Lf[4096 + ws_ * 1024 + r * 64 + ln] = o1[r];
        }
        if (lg == 0) Lx[ws_][lq] = lt;
    }
    __syncthreads();
    if (g == 0) {
        float inv = 1.0f / (lt + Lx[ws_][lq]);
        const int b = bh >> 4, h = bh & 15;
#pragma unroll
        for (int r = 0; r < 16; r++) {
            int qrow = (r & 3) + 8 * (r >> 2) + 4 * lg;
            float iv = __shfl(inv, qrow);
            float* op = out + ((long)(b * SQ + q0w + qrow)) * 1024 + h * 64 + lq;
            op[0]  = (o0[r] + Lf[ws_ * 1024 + r * 64 + ln]) * iv;
            op[32] = (o1[r] + Lf[4096 + ws_ * 1024 + r * 64 + ln]) * iv;
        }
    }
#undef STAGE
#undef QKT
#undef SMPV
}

extern "C" void kernel_launch(void* const* d_in, const int* in_sizes, int n_in,
                              void* d_out, int out_size, void* d_ws, size_t ws_size,
                              hipStream_t stream) {
    const float* x = (const float*)d_in[0];
    const float* w = (const float*)d_in[1];
    short* ws = (short*)d_ws;
    short* xbf = (short*)d_out;                  // d_out as scratch; attn overwrites last
    short* wtb = (short*)d_out + 4194304;
    cvt_all<<<2816, 256, 0, stream>>>(x, w, xbf, wtb);
    qkv_gemm<<<256, 512, 0, stream>>>(xbf, wtb, ws);
    attn<<<512, 512, 0, stream>>>(ws, ws + BB * HB * SQ * DH,
                                  ws + 2 * BB * HB * SQ * DH, (float*)d_out);
}

// Round 20
// 88.805 us; speedup vs baseline: 2.0520x; 1.0133x over previous
//
#include <hip/hip_runtime.h>
#include <hip/hip_bf16.h>

#define HB 16
#define DH 64
#define SQ 2048
#define BB 2

using f32x4 = __attribute__((ext_vector_type(4))) float;
using f32x16 = __attribute__((ext_vector_type(16))) float;
using s16x8 = __attribute__((ext_vector_type(8))) short;

__device__ __forceinline__ unsigned bfr(float f) {
    union { float f; unsigned u; } v; v.f = f;
    return (v.u + 0x7fffu + ((v.u >> 16) & 1u)) >> 16;
}
__device__ __forceinline__ unsigned pk2(float a, float b) { return bfr(a) | (bfr(b) << 16); }
__device__ __forceinline__ short f2bf(float f) { return (short)bfr(f); }

// row-stride-64-short tiles, 16B-chunk XOR swizzle s = r&7
__device__ __forceinline__ int swz64(int r, int c) {
    return r * 64 + ((((c >> 3) ^ (r & 7)) & 7) << 3) + (c & 7);
}
// row-stride-32-short tiles: chunk ^= (r>>1)&3
__device__ __forceinline__ int swz32(int r, int c) {
    return r * 32 + ((((c >> 3) ^ ((r >> 1) & 3)) & 3) << 3) + (c & 7);
}

__device__ __forceinline__ void gll16(const short* g, short* l) {
    __builtin_amdgcn_global_load_lds(
        (const __attribute__((address_space(1))) unsigned int*)(uintptr_t)g,
        (__attribute__((address_space(3))) unsigned int*)(uintptr_t)l, 16, 0, 0);
}

// ---- combined pre-pass: X fp32->bf16 (bid<2048) | W -> WT bf16 (bid>=2048) ----
__device__ __forceinline__ int swzT(int n, int k) {
    return n * 64 + ((((k >> 3) ^ ((n >> 2) & 7)) & 7) << 3) + (k & 7);
}
__global__ __launch_bounds__(256) void cvt_all(
    const float* __restrict__ x, const float* __restrict__ w,
    short* __restrict__ xb, short* __restrict__ wt)
{
    __shared__ short T[64 * 64];
    int bid = blockIdx.x;
    int t = threadIdx.x;
    if (bid < 2048) {
        int i = (bid * 256 + t) * 8;
        float4 v0 = *(const float4*)&x[i];
        float4 v1 = *(const float4*)&x[i + 4];
        uint4 u;
        u.x = pk2(v0.x, v0.y); u.y = pk2(v0.z, v0.w);
        u.z = pk2(v1.x, v1.y); u.w = pk2(v1.z, v1.w);
        *(uint4*)&xb[i] = u;
        return;
    }
    bid -= 2048;                                // 768 = 3 * 16 * 16
    int nt = bid & 15, kt = (bid >> 4) & 15, p = bid >> 8;
    const float* wp = w + p * 1048576 + (kt * 64) * 1024 + nt * 64;
    short* wtp = wt + p * 1048576 + (nt * 64) * 1024 + kt * 64;
#pragma unroll
    for (int ps = 0; ps < 4; ps++) {
        int idx = ps * 1024 + t * 4;
        int r = idx >> 6, c = idx & 63;
        float4 v = *(const float4*)&wp[r * 1024 + c];
        T[swzT(c + 0, r)] = f2bf(v.x);
        T[swzT(c + 1, r)] = f2bf(v.y);
        T[swzT(c + 2, r)] = f2bf(v.z);
        T[swzT(c + 3, r)] = f2bf(v.w);
    }
    __syncthreads();
#pragma unroll
    for (int ps = 0; ps < 2; ps++) {
        int idx = ps * 2048 + t * 8;
        int n = idx >> 6, kc = idx & 63;
        s16x8 vv = *(const s16x8*)&T[swzT(n, kc)];
        *(s16x8*)&wtp[n * 1024 + kc] = vv;
    }
}

// ---- main GEMM: p-fused 128x384, BK=64, dbuf prefetch (16 iters) ----
__global__ __launch_bounds__(512, 1) void qkv_gemm(
    const short* __restrict__ xb, const short* __restrict__ wt, short* __restrict__ ws)
{
    __shared__ short Xs[2][128 * 64];    // 32 KB
    __shared__ short Ns[2][384 * 64];    // 96 KB, p-major rows [3][128]
    const int tid = threadIdx.x;
    const int wv = tid >> 6, ln = tid & 63;
    const int bid = blockIdx.x;
    const int swz = (bid & 7) * 32 + (bid >> 3);  // XCD = 32 m-tiles x 1 n-group
    const int m0 = (swz & 31) * 128;
    const int n0 = (swz >> 5) * 128;

    const int wm = (wv >> 2) * 64, wn = (wv & 3) * 96;
    const int lr = ln & 15, lk = (ln >> 4) * 8;
    // staging: 8-row 1KB calls; lane -> row ln>>3, chunk ln&7 (swz64 inverse)
    const int sr8 = ln >> 3;
    const int csw = (((ln & 7) ^ ((ln >> 3) & 7)) & 7) * 8;

    f32x4 acc[4][6] = {};

    // 8 gll16/thread per stage: X 2 calls (rows wv*16+8c), N 6 calls (rows wv*48+8c)
    // Ns row rb in [0,384) p-major: p = rb>>7, col-row nr = rb&127
#define GSTAGE(k0_, bf_) do {                                                   \
        _Pragma("unroll")                                                       \
        for (int c = 0; c < 2; c++)                                             \
            gll16(&xb[(m0 + wv * 16 + c * 8 + sr8) * 1024 + (k0_) + csw],       \
                  &Xs[bf_][(wv * 16 + c * 8) * 64]);                            \
        _Pragma("unroll")                                                       \
        for (int c = 0; c < 6; c++) {                                           \
            int rb = wv * 48 + c * 8;                                           \
            int p_ = rb >> 7, nr = rb & 127;                                    \
            gll16(&wt[p_ * 1048576 + (n0 + nr + sr8) * 1024 + (k0_) + csw],     \
                  &Ns[bf_][rb * 64]);                                           \
        }                                                                       \
    } while (0)

#define GCOMP(bf_) do {                                                         \
        _Pragma("unroll")                                                       \
        for (int kk = 0; kk < 2; kk++) {                                        \
            s16x8 af[4], bg[6];                                                 \
            _Pragma("unroll")                                                   \
            for (int i = 0; i < 4; i++)                                         \
                af[i] = *(const s16x8*)&Xs[bf_][swz64(wm + i * 16 + lr, kk * 32 + lk)]; \
            _Pragma("unroll")                                                   \
            for (int j = 0; j < 6; j++)                                         \
                bg[j] = *(const s16x8*)&Ns[bf_][swz64(wn + j * 16 + lr, kk * 32 + lk)]; \
            __builtin_amdgcn_s_setprio(1);                                      \
            _Pragma("unroll")                                                   \
            for (int i = 0; i < 4; i++)                                         \
                _Pragma("unroll")                                               \
                for (int j = 0; j < 6; j++)                                     \
                    acc[i][j] = __builtin_amdgcn_mfma_f32_16x16x32_bf16(af[i], bg[j], acc[i][j], 0, 0, 0); \
            __builtin_amdgcn_s_setprio(0);                                      \
        }                                                                       \
    } while (0)

    GSTAGE(0, 0);
    __syncthreads();
    for (int t = 0; t < 16; t++) {
        int cur = t & 1;
        if (t < 15) GSTAGE((t + 1) * 64, cur ^ 1);   // issue next tile first
        GCOMP(cur);                                   // compute hides the loads
        __syncthreads();                              // drain once per 64-K tile
    }

    short* qws = ws;
    short* kws = ws + BB * HB * SQ * DH;
    short* vtw = ws + 2 * BB * HB * SQ * DH;
#pragma unroll
    for (int i = 0; i < 4; i++) {
#pragma unroll
        for (int r = 0; r < 4; r++) {
            int row = m0 + wm + i * 16 + (ln >> 4) * 4 + r;
            int b = row >> 11, s = row & 2047;
#pragma unroll
            for (int j = 0; j < 6; j++) {
                int c = wn + j * 16 + (ln & 15);
                int p = c >> 7;
                int gcol = n0 + (c & 127);
                int h = gcol >> 6, dhi = gcol & 63;
                float v = acc[i][j][r];
                if (p == 0)      qws[((b * HB + h) * SQ + s) * DH + dhi] = f2bf(v * 0.1803368801f);
                else if (p == 1) kws[((b * HB + h) * SQ + s) * DH + dhi] = f2bf(v);
                else             vtw[((b * HB + h) * DH + dhi) * SQ + s] = f2bf(v);
            }
        }
    }
#undef GSTAGE
#undef GCOMP
}

// ---- flash attention: KVBLK=32, quad-buffered distance-3, counted vmcnt,
//      T15 pipeline; 4 q-subtiles x 2 kv-groups ----
__global__ __launch_bounds__(512) void attn(
    const short* __restrict__ qws, const short* __restrict__ kws,
    const short* __restrict__ vtw, float* __restrict__ out)
{
    __shared__ __align__(16) short smem[32768];   // 64KB: [g 2][buf 4][K 2048 | V 2048]
    __shared__ float Lx[4][32];
    const int tid = threadIdx.x, wv = tid >> 6, ln = tid & 63;
    const int ws_ = wv & 3, g = wv >> 2;
    const int bid = blockIdx.x;
    const int swz = (bid & 7) * 64 + (bid >> 3);  // bijective (512%8==0)
    const int qt = swz & 15, bh = swz >> 4;
    const short* Q = qws + bh * SQ * DH;
    const short* K = kws + bh * SQ * DH;
    const short* VT = vtw + bh * DH * SQ;
    const int lq = ln & 31, lg = ln >> 5;
    const int q0w = qt * 128 + ws_ * 32;
    const int kvbase = g * 1024;

    const int klo = (ws_ * 8 + (ln >> 3)) * DH + (((ln & 7) ^ ((ln >> 3) & 7)) & 7) * 8;
    const int vr = ln >> 2;
    const int vlo = (ws_ * 16 + vr) * SQ + (((ln & 3) ^ ((vr >> 1) & 3)) & 3) * 8;

    s16x8 qf[4];
#pragma unroll
    for (int ks = 0; ks < 4; ks++)
        qf[ks] = *(const s16x8*)&Q[(q0w + lq) * DH + ks * 16 + lg * 8];

    f32x16 o0 = {}, o1 = {};
    float l = 0.f;

#define STAGE(t, bf_) do {                                          \
        short* Kd = smem + g * 16384 + (bf_) * 4096;                \
        const short* Kt = K + (kvbase + (t) * 32) * DH;             \
        const short* Vt = VT + kvbase + (t) * 32;                   \
        gll16(Kt + klo, Kd + ws_ * 512);                            \
        gll16(Vt + vlo, Kd + 2048 + ws_ * 512);                     \
    } while (0)

#define QKT(bf_, S_) do {                                                      \
        const short* Kr = smem + g * 16384 + (bf_) * 4096;                     \
        __builtin_amdgcn_s_setprio(1);                                         \
        _Pragma("unroll")                                                      \
        for (int ks = 0; ks < 4; ks++) {                                       \
            s16x8 ka = *(const s16x8*)&Kr[swz64(lq, ks * 16 + lg * 8)];        \
            S_ = __builtin_amdgcn_mfma_f32_32x32x16_bf16(ka, qf[ks], S_, 0, 0, 0); \
        }                                                                      \
        __builtin_amdgcn_s_setprio(0);                                         \
    } while (0)

#define SMPV(bf_, S_) do {                                                     \
        const short* Vr = smem + g * 16384 + (bf_) * 4096 + 2048;              \
        float p[16];                                                           \
        _Pragma("unroll")                                                      \
        for (int i = 0; i < 16; i++) p[i] = __builtin_amdgcn_exp2f(S_[i]);     \
        float a0 = 0.f, a1 = 0.f, a2 = 0.f, a3 = 0.f;                          \
        _Pragma("unroll")                                                      \
        for (int i = 0; i < 16; i += 4) {                                      \
            a0 += p[i]; a1 += p[i + 1]; a2 += p[i + 2]; a3 += p[i + 3];        \
        }                                                                      \
        l += (a0 + a1) + (a2 + a3);                                            \
        unsigned u[8];                                                         \
        _Pragma("unroll")                                                      \
        for (int qd = 0; qd < 4; qd++) {                                       \
            asm("v_cvt_pk_bf16_f32 %0, %1, %2" : "=v"(u[qd * 2]) : "v"(p[qd * 4 + 0]), "v"(p[qd * 4 + 1])); \
            asm("v_cvt_pk_bf16_f32 %0, %1, %2" : "=v"(u[qd * 2 + 1]) : "v"(p[qd * 4 + 2]), "v"(p[qd * 4 + 3])); \
        }                                                                      \
        _Pragma("unroll")                                                      \
        for (int m2 = 0; m2 < 2; m2++)                                         \
            _Pragma("unroll")                                                  \
            for (int j = 0; j < 2; j++)                                        \
                asm("v_permlane32_swap_b32 %0, %1"                             \
                    : "+v"(u[(2 * m2) * 2 + j]), "+v"(u[(2 * m2 + 1) * 2 + j])); \
        __builtin_amdgcn_s_setprio(1);                                         \
        _Pragma("unroll")                                                      \
        for (int ks = 0; ks < 2; ks++) {                                       \
            union { unsigned w[4]; s16x8 v; } pa;                              \
            pa.w[0] = u[4 * ks + 0];                                           \
            pa.w[1] = u[4 * ks + 1];                                           \
            pa.w[2] = u[4 * ks + 2];                                           \
            pa.w[3] = u[4 * ks + 3];                                           \
            s16x8 vb0 = *(const s16x8*)&Vr[swz32(lq, ks * 16 + lg * 8)];       \
            s16x8 vb1 = *(const s16x8*)&Vr[swz32(32 + lq, ks * 16 + lg * 8)];  \
            o0 = __builtin_amdgcn_mfma_f32_32x32x16_bf16(pa.v, vb0, o0, 0, 0, 0); \
            o1 = __builtin_amdgcn_mfma_f32_32x32x16_bf16(pa.v, vb1, o1, 0, 0, 0); \
        }                                                                      \
        __builtin_amdgcn_s_setprio(0);                                         \
    } while (0)

    STAGE(0, 0);
    STAGE(1, 1);
    STAGE(2, 2);
    asm volatile("s_waitcnt vmcnt(2)\n\ts_barrier" ::: "memory");
    f32x16 sA = {}, sB = {};
    QKT(0, sA);
#pragma unroll
    for (int t = 0; t < 32; t++) {
        if (t < 29) STAGE(t + 3, (t + 3) & 3);
        if (t < 31) {
            if (t & 1) QKT((t + 1) & 3, sA);
            else       QKT((t + 1) & 3, sB);
        }
        if (t & 1) SMPV(t & 3, sB);
        else       SMPV(t & 3, sA);
        if (t & 1) sB = (f32x16){};
        else       sA = (f32x16){};
        if (t < 29) asm volatile("s_waitcnt vmcnt(2)\n\ts_barrier" ::: "memory");
        else        asm volatile("s_waitcnt vmcnt(0)\n\ts_barrier" ::: "memory");
    }

    float lt = l + __shfl_xor(l, 32);
    float* Lf = (float*)smem;
    if (g == 1) {
#pragma unroll
        for (int r = 0; r < 16; r++) {
            Lf[ws_ * 1024 + r * 64 + ln] = o0[r];
            Lf[4096 + ws_ * 1024 + r * 64 + ln] = o1[r];
        }
        if (lg == 0) Lx[ws_][lq] = lt;
    }
    __syncthreads();
    if (g == 0) {
        float inv = 1.0f / (lt + Lx[ws_][lq]);
        const int b = bh >> 4, h = bh & 15;
#pragma unroll
        for (int r = 0; r < 16; r++) {
            int qrow = (r & 3) + 8 * (r >> 2) + 4 * lg;
            float iv = __shfl(inv, qrow);
            float* op = out + ((long)(b * SQ + q0w + qrow)) * 1024 + h * 64 + lq;
            op[0]  = (o0[r] + Lf[ws_ * 1024 + r * 64 + ln]) * iv;
            op[32] = (o1[r] + Lf[4096 + ws_ * 1024 + r * 64 + ln]) * iv;
        }
    }
#undef STAGE
#undef QKT
#undef SMPV
}

extern "C" void kernel_launch(void* const* d_in, const int* in_sizes, int n_in,
                              void* d_out, int out_size, void* d_ws, size_t ws_size,
                              hipStream_t stream) {
    const float* x = (const float*)d_in[0];
    const float* w = (const float*)d_in[1];
    short* ws = (short*)d_ws;
    short* xbf = (short*)d_out;                  // d_out as scratch; attn overwrites last
    short* wtb = (short*)d_out + 4194304;
    cvt_all<<<2816, 256, 0, stream>>>(x, w, xbf, wtb);
    qkv_gemm<<<256, 512, 0, stream>>>(xbf, wtb, ws);
    attn<<<512, 512, 0, stream>>>(ws, ws + BB * HB * SQ * DH,
                                  ws + 2 * BB * HB * SQ * DH, (float*)d_out);
}